// Round 6
// baseline (1188.629 us; speedup 1.0000x reference)
//
#include <hip/hip_runtime.h>

// Problem: 2-layer GCN (GCNConv with analytic self-loops) + mean-pool + FC.
// N=100000 nodes, E=1.6M edges, F=128, H=128, H2=64, B=50 graphs, C=10.
// Strategy: build CSR-by-dst once (atomic count -> scan -> counting sort with
// precomputed edge norms packed as int2{src,w}), then gather-only aggregation.
// fp32 throughout for exactness.
// R1: count_batch atomics (567us) -> 50 binary searches over sorted batch.
// R4: GEMM rework: xs[r][k] untransposed, 4x4 consecutive tile, ds_read_b128.
// R5: aggregate was latency-bound (200us, HBM 16%, VALU 12%): one 512B
// row-gather per edge, 4 in flight. Now: FW=128 -> two 32-lane halves each
// cover the row with float4/lane, alternating edges (2 edges/issue, 8 in
// flight); FW=64 -> four 16-lane quarters (4 edges/issue). Cross-group
// combine via __shfl_xor once per node. CSR packed int2 -> one 8B broadcast
// load per edge, one 8B scatter store in fill_csr.

#define IDX (blockIdx.x * (int)blockDim.x + (int)threadIdx.x)

// ---------------- degree / normalization ----------------
__global__ void count_deg(const int* __restrict__ dst, int* __restrict__ cnt, int E) {
    int e = IDX;
    if (e < E) atomicAdd(&cnt[dst[e]], 1);
}

__global__ void compute_dinv(const int* __restrict__ cnt, float* __restrict__ dinv,
                             float* __restrict__ winv, int n) {
    int i = IDX;
    if (i < n) {
        float d = 1.0f + (float)cnt[i];      // deg includes self-loop
        dinv[i] = 1.0f / sqrtf(d);
        winv[i] = 1.0f / d;                  // self-loop weight
    }
}

// ---------------- exclusive scan over cnt (N=100000, 1024 items/block) ------
__global__ void scan1(const int* __restrict__ cnt, int* __restrict__ rs,
                      int* __restrict__ bsum, int n) {
    __shared__ int lds[256];
    int t = threadIdx.x;
    int base = blockIdx.x * 1024 + t * 4;
    int c0 = 0, c1 = 0, c2 = 0, c3 = 0;
    if (base + 3 < n) {
        int4 v = *(const int4*)&cnt[base];
        c0 = v.x; c1 = v.y; c2 = v.z; c3 = v.w;
    } else {
        if (base     < n) c0 = cnt[base];
        if (base + 1 < n) c1 = cnt[base + 1];
        if (base + 2 < n) c2 = cnt[base + 2];
        if (base + 3 < n) c3 = cnt[base + 3];
    }
    int s = c0 + c1 + c2 + c3;
    lds[t] = s; __syncthreads();
    for (int off = 1; off < 256; off <<= 1) {
        int v = (t >= off) ? lds[t - off] : 0;
        __syncthreads();
        lds[t] += v;
        __syncthreads();
    }
    int incl = lds[t];
    int excl = incl - s;
    if (t == 255) bsum[blockIdx.x] = incl;
    if (base     < n) rs[base]     = excl;
    if (base + 1 < n) rs[base + 1] = excl + c0;
    if (base + 2 < n) rs[base + 2] = excl + c0 + c1;
    if (base + 3 < n) rs[base + 3] = excl + c0 + c1 + c2;
}

__global__ void scan2(int* __restrict__ bsum, int nb) {   // nb <= 128
    __shared__ int lds[128];
    int t = threadIdx.x;
    int v = (t < nb) ? bsum[t] : 0;
    lds[t] = v; __syncthreads();
    for (int off = 1; off < 128; off <<= 1) {
        int u = (t >= off) ? lds[t - off] : 0;
        __syncthreads();
        lds[t] += u;
        __syncthreads();
    }
    if (t < nb) bsum[t] = lds[t] - v;   // exclusive
}

__global__ void scan3(int* __restrict__ rs, const int* __restrict__ bsum, int n, int E) {
    int i = IDX;
    if (i < n) rs[i] += bsum[i >> 10];
    if (i == 0) rs[n] = E;
}

// ---------------- CSR fill (counting sort by dst, packed {src, w}) ----------
__global__ void fill_csr(const int* __restrict__ src, const int* __restrict__ dst,
                         const int* __restrict__ rs, int* __restrict__ cursor,
                         const float* __restrict__ dinv,
                         int2* __restrict__ csr_pk, int E) {
    int e = IDX;
    if (e < E) {
        int d = dst[e], s = src[e];
        int p = rs[d] + atomicAdd(&cursor[d], 1);
        csr_pk[p] = make_int2(s, __float_as_int(dinv[s] * dinv[d]));
    }
}

// ---------------- fp32 GEMM: Y[nrows x outw] = X[nrows x 128] @ W[128 x outw]
// 64 rows x 64 cols per block; thread owns 4 consecutive rows x 4 consecutive
// cols; k unrolled by 4 -> all LDS reads are ds_read_b128, conflict-free.
__global__ __launch_bounds__(256) void gemm_k128(const float* __restrict__ X,
        const float* __restrict__ W, float* __restrict__ Y, int nrows, int outw) {
    __shared__ float ws[128][64];   // ws[k][c]
    __shared__ float xs[64][128];   // xs[r][k]  (same layout as global)
    const int t = threadIdx.x;
    const int row0 = blockIdx.x * 64;
    const int c0 = blockIdx.y * 64;

    #pragma unroll
    for (int i = 0; i < 8; ++i) {          // 128x64 W tile, float4 in+out
        int idx = i * 256 + t;
        int k = idx >> 4, cq = idx & 15;
        float4 v = *(const float4*)&W[(size_t)k * outw + c0 + cq * 4];
        *(float4*)&ws[k][cq * 4] = v;
    }
    #pragma unroll
    for (int i = 0; i < 8; ++i) {          // 64x128 X tile, direct layout
        int idx = i * 256 + t;
        int r = idx >> 5, kq = idx & 31;
        float4 v = make_float4(0.f, 0.f, 0.f, 0.f);
        if (row0 + r < nrows) v = *(const float4*)&X[(size_t)(row0 + r) * 128 + kq * 4];
        *(float4*)&xs[r][kq * 4] = v;
    }
    __syncthreads();

    const int r0  = (t >> 4) * 4;   // rows r0..r0+3
    const int cc0 = (t & 15) * 4;   // cols cc0..cc0+3
    float acc[4][4] = {};
    #pragma unroll 2
    for (int k0 = 0; k0 < 128; k0 += 4) {
        float xv[4][4], wv[4][4];
        #pragma unroll
        for (int i = 0; i < 4; ++i)
            *(float4*)xv[i] = *(const float4*)&xs[r0 + i][k0];
        #pragma unroll
        for (int kk = 0; kk < 4; ++kk)
            *(float4*)wv[kk] = *(const float4*)&ws[k0 + kk][cc0];
        #pragma unroll
        for (int i = 0; i < 4; ++i)
            #pragma unroll
            for (int kk = 0; kk < 4; ++kk)
                #pragma unroll
                for (int j = 0; j < 4; ++j)
                    acc[i][j] = fmaf(xv[i][kk], wv[kk][j], acc[i][j]);
    }
    #pragma unroll
    for (int i = 0; i < 4; ++i) {
        int row = row0 + r0 + i;
        if (row < nrows)
            *(float4*)&Y[(size_t)row * outw + c0 + cc0] = *(const float4*)acc[i];
    }
}

// ---------------- gather aggregation: out = relu(agg + h*winv + bias) -------
// One wave per node. FW=128: two 32-lane halves, each covers the 128-float row
// with float4/lane; halves take alternating edges. FW=64: four 16-lane
// quarters, stride-4 edges. Cross-group combine via shfl_xor once per node.
template<int FW, bool POOL>
__global__ __launch_bounds__(256) void aggregate(
        const float* __restrict__ h, const int* __restrict__ rs,
        const int2* __restrict__ csr_pk,
        const float* __restrict__ winv, const float* __restrict__ bias,
        const int* __restrict__ batch, float* __restrict__ pooled,
        float* __restrict__ out, int n) {
    int node = blockIdx.x * 4 + ((int)threadIdx.x >> 6);
    int lane = (int)threadIdx.x & 63;
    if (node >= n) return;
    const int b0 = rs[node], b1 = rs[node + 1];

    constexpr int NG   = (FW == 128) ? 2 : 4;    // edge groups per wave
    const int grp = lane / (64 / NG);            // which edge group
    const int fl  = lane % (64 / NG);            // float4 index within row

    float4 acc = make_float4(0.f, 0.f, 0.f, 0.f);
    int e = b0 + grp;

    if (FW == 128) {
        // unroll 4: edges e, e+2, e+4, e+6 for this half (8 edges/wave-iter)
        for (; e + 6 < b1; e += 8) {
            int2 p0 = csr_pk[e],     p1 = csr_pk[e + 2];
            int2 p2 = csr_pk[e + 4], p3 = csr_pk[e + 6];
            float4 v0 = *(const float4*)&h[(size_t)p0.x * 128 + fl * 4];
            float4 v1 = *(const float4*)&h[(size_t)p1.x * 128 + fl * 4];
            float4 v2 = *(const float4*)&h[(size_t)p2.x * 128 + fl * 4];
            float4 v3 = *(const float4*)&h[(size_t)p3.x * 128 + fl * 4];
            float w0 = __int_as_float(p0.y), w1 = __int_as_float(p1.y);
            float w2 = __int_as_float(p2.y), w3 = __int_as_float(p3.y);
            acc.x = fmaf(v0.x, w0, fmaf(v1.x, w1, fmaf(v2.x, w2, fmaf(v3.x, w3, acc.x))));
            acc.y = fmaf(v0.y, w0, fmaf(v1.y, w1, fmaf(v2.y, w2, fmaf(v3.y, w3, acc.y))));
            acc.z = fmaf(v0.z, w0, fmaf(v1.z, w1, fmaf(v2.z, w2, fmaf(v3.z, w3, acc.z))));
            acc.w = fmaf(v0.w, w0, fmaf(v1.w, w1, fmaf(v2.w, w2, fmaf(v3.w, w3, acc.w))));
        }
        for (; e < b1; e += 2) {
            int2 p = csr_pk[e];
            float4 v = *(const float4*)&h[(size_t)p.x * 128 + fl * 4];
            float w = __int_as_float(p.y);
            acc.x = fmaf(v.x, w, acc.x); acc.y = fmaf(v.y, w, acc.y);
            acc.z = fmaf(v.z, w, acc.z); acc.w = fmaf(v.w, w, acc.w);
        }
    } else {
        // unroll 2: edges e, e+4 for this quarter (8 edges/wave-iter)
        for (; e + 4 < b1; e += 8) {
            int2 p0 = csr_pk[e], p1 = csr_pk[e + 4];
            float4 v0 = *(const float4*)&h[(size_t)p0.x * 64 + fl * 4];
            float4 v1 = *(const float4*)&h[(size_t)p1.x * 64 + fl * 4];
            float w0 = __int_as_float(p0.y), w1 = __int_as_float(p1.y);
            acc.x = fmaf(v0.x, w0, fmaf(v1.x, w1, acc.x));
            acc.y = fmaf(v0.y, w0, fmaf(v1.y, w1, acc.y));
            acc.z = fmaf(v0.z, w0, fmaf(v1.z, w1, acc.z));
            acc.w = fmaf(v0.w, w0, fmaf(v1.w, w1, acc.w));
        }
        for (; e < b1; e += 4) {
            int2 p = csr_pk[e];
            float4 v = *(const float4*)&h[(size_t)p.x * 64 + fl * 4];
            float w = __int_as_float(p.y);
            acc.x = fmaf(v.x, w, acc.x); acc.y = fmaf(v.y, w, acc.y);
            acc.z = fmaf(v.z, w, acc.z); acc.w = fmaf(v.w, w, acc.w);
        }
    }

    // combine edge groups (butterfly over group bits of the lane id)
    if (FW == 64) {
        acc.x += __shfl_xor(acc.x, 16); acc.y += __shfl_xor(acc.y, 16);
        acc.z += __shfl_xor(acc.z, 16); acc.w += __shfl_xor(acc.w, 16);
    }
    acc.x += __shfl_xor(acc.x, 32); acc.y += __shfl_xor(acc.y, 32);
    acc.z += __shfl_xor(acc.z, 32); acc.w += __shfl_xor(acc.w, 32);

    const float wself = winv[node];
    float4 hv = *(const float4*)&h[(size_t)node * FW + fl * 4];
    float4 bv = *(const float4*)&bias[fl * 4];
    float4 o;
    o.x = fmaxf(fmaf(hv.x, wself, acc.x) + bv.x, 0.f);
    o.y = fmaxf(fmaf(hv.y, wself, acc.y) + bv.y, 0.f);
    o.z = fmaxf(fmaf(hv.z, wself, acc.z) + bv.z, 0.f);
    o.w = fmaxf(fmaf(hv.w, wself, acc.w) + bv.w, 0.f);

    if (grp == 0) {
        *(float4*)&out[(size_t)node * FW + fl * 4] = o;
        if (POOL) {
            float* pb = &pooled[(size_t)batch[node] * 64 + fl * 4];
            atomicAdd(pb + 0, o.x); atomicAdd(pb + 1, o.y);
            atomicAdd(pb + 2, o.z); atomicAdd(pb + 3, o.w);
        }
    }
}

// ---------------- pooling counts (batch is SORTED -> binary search) ---------
__global__ void graph_counts(const int* __restrict__ batch, int* __restrict__ cntB,
                             int n, int B) {
    int b = (int)threadIdx.x;
    if (b < B) {
        int lo = 0, hi = n;                 // lower_bound(b)
        while (lo < hi) { int mid = (lo + hi) >> 1; if (batch[mid] < b) lo = mid + 1; else hi = mid; }
        int start = lo;
        lo = 0; hi = n;                     // upper_bound(b)
        while (lo < hi) { int mid = (lo + hi) >> 1; if (batch[mid] <= b) lo = mid + 1; else hi = mid; }
        cntB[b] = lo - start;
    }
}

__global__ void fc_kernel(const float* __restrict__ pooled, const int* __restrict__ cntB,
                          const float* __restrict__ Wfc, const float* __restrict__ bfc,
                          float* __restrict__ out) {
    int t = IDX;
    if (t < 50 * 10) {
        int b = t / 10, c = t % 10;
        float inv = 1.0f / fmaxf((float)cntB[b], 1.0f);
        float s = bfc[c];
        #pragma unroll
        for (int f = 0; f < 64; ++f)
            s = fmaf(pooled[b*64 + f] * inv, Wfc[f*10 + c], s);
        out[t] = s;
    }
}

extern "C" void kernel_launch(void* const* d_in, const int* in_sizes, int n_in,
                              void* d_out, int out_size, void* d_ws, size_t ws_size,
                              hipStream_t stream) {
    const float* x     = (const float*)d_in[0];
    const int*   ei    = (const int*)d_in[1];
    const int*   batch = (const int*)d_in[2];
    const float* W1    = (const float*)d_in[3];
    const float* b1    = (const float*)d_in[4];
    const float* W2    = (const float*)d_in[5];
    const float* b2    = (const float*)d_in[6];
    const float* Wfc   = (const float*)d_in[7];
    const float* bfc   = (const float*)d_in[8];
    float* out = (float*)d_out;

    const int n = in_sizes[2];          // 100000
    const int E = in_sizes[1] / 2;      // 1600000
    const int* src = ei;
    const int* dst = ei + E;

    // bump-allocate workspace (256B aligned regions)
    char* p = (char*)d_ws;
    auto alloc = [&](size_t bytes) { char* r = p; p += (bytes + 255) & ~(size_t)255; return r; };
    int*   cnt     = (int*)  alloc((size_t)n * 4);
    int*   cursor  = (int*)  alloc((size_t)n * 4);
    float* pooled  = (float*)alloc(50 * 64 * 4);
    size_t zbytes  = (size_t)(p - (char*)d_ws);      // zero-init region
    int*   cntB    = (int*)  alloc(50 * 4);
    int*   bsum    = (int*)  alloc(128 * 4);
    int*   rs      = (int*)  alloc((size_t)(n + 1) * 4);
    int2*  csr_pk  = (int2*) alloc((size_t)E * 8);
    float* dinv    = (float*)alloc((size_t)n * 4);
    float* winv    = (float*)alloc((size_t)n * 4);
    float* h_raw   = (float*)alloc((size_t)n * 128 * 4);
    float* h_act   = (float*)alloc((size_t)n * 128 * 4);

    hipMemsetAsync(d_ws, 0, zbytes, stream);

    int eb    = (E + 255) / 256;
    int nb256 = (n + 255) / 256;
    int nscan = (n + 1023) / 1024;      // 98 blocks (<=128 for scan2)

    count_deg<<<eb, 256, 0, stream>>>(dst, cnt, E);
    compute_dinv<<<nb256, 256, 0, stream>>>(cnt, dinv, winv, n);
    scan1<<<nscan, 256, 0, stream>>>(cnt, rs, bsum, n);
    scan2<<<1, 128, 0, stream>>>(bsum, nscan);
    scan3<<<nb256, 256, 0, stream>>>(rs, bsum, n, E);
    fill_csr<<<eb, 256, 0, stream>>>(src, dst, rs, cursor, dinv, csr_pk, E);

    // layer 1: h_raw = x @ W1 ; h_act = relu(agg(h_raw) + h_raw*winv + b1)
    dim3 g1((n + 63) / 64, 2);
    gemm_k128<<<g1, 256, 0, stream>>>(x, W1, h_raw, n, 128);
    int nagg = (n + 3) / 4;
    aggregate<128, false><<<nagg, 256, 0, stream>>>(h_raw, rs, csr_pk,
                                                    winv, b1, batch, pooled, h_act, n);

    // layer 2: h_raw(:, :64) = h_act @ W2 ; h_act(:, :64) = relu(...) + fused pooling
    dim3 g2((n + 63) / 64, 1);
    gemm_k128<<<g2, 256, 0, stream>>>(h_act, W2, h_raw, n, 64);
    graph_counts<<<1, 64, 0, stream>>>(batch, cntB, n, 50);
    aggregate<64, true><<<nagg, 256, 0, stream>>>(h_raw, rs, csr_pk,
                                                  winv, b2, batch, pooled, h_act, n);

    fc_kernel<<<1, 512, 0, stream>>>(pooled, cntB, Wfc, bfc, out);
}

// Round 7
// 665.007 us; speedup vs baseline: 1.7874x; 1.7874x over previous
//
#include <hip/hip_runtime.h>

// Problem: 2-layer GCN (GCNConv with analytic self-loops) + mean-pool + FC.
// N=100000 nodes, E=1.6M edges, F=128, H=128, H2=64, B=50 graphs, C=10.
// Strategy: build CSR-by-dst once (atomic count -> scan -> counting sort with
// precomputed edge norms packed as int2{src,w}), then gather-only aggregation.
// fp32 throughout for exactness.
// R1: count_batch atomics (567us) -> 50 binary searches over sorted batch.
// R4: GEMM rework: xs[r][k] untransposed, 4x4 consecutive tile, ds_read_b128.
// R5 FAILED: sharding the row across 32/16-lane sub-groups (multi-row per
// memory instruction) quadrupled aggregate time (200->810us) at identical
// FETCH_SIZE -- the one-row-per-wave-instruction pattern is what the
// coalescer runs at full rate. Reverted.
// R6: R4 aggregate structure restored; unroll 4->8 (8 independent row
// gathers in flight per wave); int2-packed CSR kept (one 8B broadcast load
// per edge, halves fill_csr scatter stores).

#define IDX (blockIdx.x * (int)blockDim.x + (int)threadIdx.x)

// ---------------- degree / normalization ----------------
__global__ void count_deg(const int* __restrict__ dst, int* __restrict__ cnt, int E) {
    int e = IDX;
    if (e < E) atomicAdd(&cnt[dst[e]], 1);
}

__global__ void compute_dinv(const int* __restrict__ cnt, float* __restrict__ dinv,
                             float* __restrict__ winv, int n) {
    int i = IDX;
    if (i < n) {
        float d = 1.0f + (float)cnt[i];      // deg includes self-loop
        dinv[i] = 1.0f / sqrtf(d);
        winv[i] = 1.0f / d;                  // self-loop weight
    }
}

// ---------------- exclusive scan over cnt (N=100000, 1024 items/block) ------
__global__ void scan1(const int* __restrict__ cnt, int* __restrict__ rs,
                      int* __restrict__ bsum, int n) {
    __shared__ int lds[256];
    int t = threadIdx.x;
    int base = blockIdx.x * 1024 + t * 4;
    int c0 = 0, c1 = 0, c2 = 0, c3 = 0;
    if (base + 3 < n) {
        int4 v = *(const int4*)&cnt[base];
        c0 = v.x; c1 = v.y; c2 = v.z; c3 = v.w;
    } else {
        if (base     < n) c0 = cnt[base];
        if (base + 1 < n) c1 = cnt[base + 1];
        if (base + 2 < n) c2 = cnt[base + 2];
        if (base + 3 < n) c3 = cnt[base + 3];
    }
    int s = c0 + c1 + c2 + c3;
    lds[t] = s; __syncthreads();
    for (int off = 1; off < 256; off <<= 1) {
        int v = (t >= off) ? lds[t - off] : 0;
        __syncthreads();
        lds[t] += v;
        __syncthreads();
    }
    int incl = lds[t];
    int excl = incl - s;
    if (t == 255) bsum[blockIdx.x] = incl;
    if (base     < n) rs[base]     = excl;
    if (base + 1 < n) rs[base + 1] = excl + c0;
    if (base + 2 < n) rs[base + 2] = excl + c0 + c1;
    if (base + 3 < n) rs[base + 3] = excl + c0 + c1 + c2;
}

__global__ void scan2(int* __restrict__ bsum, int nb) {   // nb <= 128
    __shared__ int lds[128];
    int t = threadIdx.x;
    int v = (t < nb) ? bsum[t] : 0;
    lds[t] = v; __syncthreads();
    for (int off = 1; off < 128; off <<= 1) {
        int u = (t >= off) ? lds[t - off] : 0;
        __syncthreads();
        lds[t] += u;
        __syncthreads();
    }
    if (t < nb) bsum[t] = lds[t] - v;   // exclusive
}

__global__ void scan3(int* __restrict__ rs, const int* __restrict__ bsum, int n, int E) {
    int i = IDX;
    if (i < n) rs[i] += bsum[i >> 10];
    if (i == 0) rs[n] = E;
}

// ---------------- CSR fill (counting sort by dst, packed {src, w}) ----------
__global__ void fill_csr(const int* __restrict__ src, const int* __restrict__ dst,
                         const int* __restrict__ rs, int* __restrict__ cursor,
                         const float* __restrict__ dinv,
                         int2* __restrict__ csr_pk, int E) {
    int e = IDX;
    if (e < E) {
        int d = dst[e], s = src[e];
        int p = rs[d] + atomicAdd(&cursor[d], 1);
        csr_pk[p] = make_int2(s, __float_as_int(dinv[s] * dinv[d]));
    }
}

// ---------------- fp32 GEMM: Y[nrows x outw] = X[nrows x 128] @ W[128 x outw]
// 64 rows x 64 cols per block; thread owns 4 consecutive rows x 4 consecutive
// cols; k unrolled by 4 -> all LDS reads are ds_read_b128, conflict-free.
__global__ __launch_bounds__(256) void gemm_k128(const float* __restrict__ X,
        const float* __restrict__ W, float* __restrict__ Y, int nrows, int outw) {
    __shared__ float ws[128][64];   // ws[k][c]
    __shared__ float xs[64][128];   // xs[r][k]  (same layout as global)
    const int t = threadIdx.x;
    const int row0 = blockIdx.x * 64;
    const int c0 = blockIdx.y * 64;

    #pragma unroll
    for (int i = 0; i < 8; ++i) {          // 128x64 W tile, float4 in+out
        int idx = i * 256 + t;
        int k = idx >> 4, cq = idx & 15;
        float4 v = *(const float4*)&W[(size_t)k * outw + c0 + cq * 4];
        *(float4*)&ws[k][cq * 4] = v;
    }
    #pragma unroll
    for (int i = 0; i < 8; ++i) {          // 64x128 X tile, direct layout
        int idx = i * 256 + t;
        int r = idx >> 5, kq = idx & 31;
        float4 v = make_float4(0.f, 0.f, 0.f, 0.f);
        if (row0 + r < nrows) v = *(const float4*)&X[(size_t)(row0 + r) * 128 + kq * 4];
        *(float4*)&xs[r][kq * 4] = v;
    }
    __syncthreads();

    const int r0  = (t >> 4) * 4;   // rows r0..r0+3
    const int cc0 = (t & 15) * 4;   // cols cc0..cc0+3
    float acc[4][4] = {};
    #pragma unroll 2
    for (int k0 = 0; k0 < 128; k0 += 4) {
        float xv[4][4], wv[4][4];
        #pragma unroll
        for (int i = 0; i < 4; ++i)
            *(float4*)xv[i] = *(const float4*)&xs[r0 + i][k0];
        #pragma unroll
        for (int kk = 0; kk < 4; ++kk)
            *(float4*)wv[kk] = *(const float4*)&ws[k0 + kk][cc0];
        #pragma unroll
        for (int i = 0; i < 4; ++i)
            #pragma unroll
            for (int kk = 0; kk < 4; ++kk)
                #pragma unroll
                for (int j = 0; j < 4; ++j)
                    acc[i][j] = fmaf(xv[i][kk], wv[kk][j], acc[i][j]);
    }
    #pragma unroll
    for (int i = 0; i < 4; ++i) {
        int row = row0 + r0 + i;
        if (row < nrows)
            *(float4*)&Y[(size_t)row * outw + c0 + cc0] = *(const float4*)acc[i];
    }
}

// ---------------- gather aggregation: out = relu(agg + h*winv + bias) -------
// One wave per node; ONE full row per memory instruction (64 lanes contiguous).
// FW=128: lane owns feats (2*lane, 2*lane+1) via float2. FW=64: lane owns
// feat `lane`. Unroll 8 -> 8 independent row gathers in flight per wave.
template<int FW, bool POOL>
__global__ __launch_bounds__(256) void aggregate(
        const float* __restrict__ h, const int* __restrict__ rs,
        const int2* __restrict__ csr_pk,
        const float* __restrict__ winv, const float* __restrict__ bias,
        const int* __restrict__ batch, float* __restrict__ pooled,
        float* __restrict__ out, int n) {
    int node = blockIdx.x * 4 + ((int)threadIdx.x >> 6);
    int lane = (int)threadIdx.x & 63;
    if (node >= n) return;
    const int b0 = rs[node], b1 = rs[node + 1];

    float a0 = 0.f, a1 = 0.f;
    int e = b0;
    for (; e + 8 <= b1; e += 8) {
        int2 p0 = csr_pk[e],   p1 = csr_pk[e+1], p2 = csr_pk[e+2], p3 = csr_pk[e+3];
        int2 p4 = csr_pk[e+4], p5 = csr_pk[e+5], p6 = csr_pk[e+6], p7 = csr_pk[e+7];
        float w0 = __int_as_float(p0.y), w1 = __int_as_float(p1.y);
        float w2 = __int_as_float(p2.y), w3 = __int_as_float(p3.y);
        float w4 = __int_as_float(p4.y), w5 = __int_as_float(p5.y);
        float w6 = __int_as_float(p6.y), w7 = __int_as_float(p7.y);
        if (FW == 128) {
            float2 v0 = *(const float2*)&h[(size_t)p0.x*128 + lane*2];
            float2 v1 = *(const float2*)&h[(size_t)p1.x*128 + lane*2];
            float2 v2 = *(const float2*)&h[(size_t)p2.x*128 + lane*2];
            float2 v3 = *(const float2*)&h[(size_t)p3.x*128 + lane*2];
            float2 v4 = *(const float2*)&h[(size_t)p4.x*128 + lane*2];
            float2 v5 = *(const float2*)&h[(size_t)p5.x*128 + lane*2];
            float2 v6 = *(const float2*)&h[(size_t)p6.x*128 + lane*2];
            float2 v7 = *(const float2*)&h[(size_t)p7.x*128 + lane*2];
            a0 += (v0.x*w0 + v1.x*w1) + (v2.x*w2 + v3.x*w3)
                + (v4.x*w4 + v5.x*w5) + (v6.x*w6 + v7.x*w7);
            a1 += (v0.y*w0 + v1.y*w1) + (v2.y*w2 + v3.y*w3)
                + (v4.y*w4 + v5.y*w5) + (v6.y*w6 + v7.y*w7);
        } else {
            float v0 = h[(size_t)p0.x*64 + lane];
            float v1 = h[(size_t)p1.x*64 + lane];
            float v2 = h[(size_t)p2.x*64 + lane];
            float v3 = h[(size_t)p3.x*64 + lane];
            float v4 = h[(size_t)p4.x*64 + lane];
            float v5 = h[(size_t)p5.x*64 + lane];
            float v6 = h[(size_t)p6.x*64 + lane];
            float v7 = h[(size_t)p7.x*64 + lane];
            a0 += (v0*w0 + v1*w1) + (v2*w2 + v3*w3)
                + (v4*w4 + v5*w5) + (v6*w6 + v7*w7);
        }
    }
    for (; e < b1; ++e) {
        int2 p = csr_pk[e];
        float w = __int_as_float(p.y);
        if (FW == 128) {
            float2 v = *(const float2*)&h[(size_t)p.x*128 + lane*2];
            a0 += v.x * w; a1 += v.y * w;
        } else {
            a0 += h[(size_t)p.x*64 + lane] * w;
        }
    }

    float wself = winv[node];
    if (FW == 128) {
        float2 hv = *(const float2*)&h[(size_t)node*128 + lane*2];
        float2 bv = *(const float2*)&bias[lane*2];
        float o0 = fmaxf(fmaf(hv.x, wself, a0) + bv.x, 0.f);
        float o1 = fmaxf(fmaf(hv.y, wself, a1) + bv.y, 0.f);
        *(float2*)&out[(size_t)node*128 + lane*2] = make_float2(o0, o1);
    } else {
        float hv = h[(size_t)node*64 + lane];
        float o = fmaxf(fmaf(hv, wself, a0) + bias[lane], 0.f);
        out[(size_t)node*64 + lane] = o;
        if (POOL) atomicAdd(&pooled[(size_t)batch[node]*64 + lane], o);
    }
}

// ---------------- pooling counts (batch is SORTED -> binary search) ---------
__global__ void graph_counts(const int* __restrict__ batch, int* __restrict__ cntB,
                             int n, int B) {
    int b = (int)threadIdx.x;
    if (b < B) {
        int lo = 0, hi = n;                 // lower_bound(b)
        while (lo < hi) { int mid = (lo + hi) >> 1; if (batch[mid] < b) lo = mid + 1; else hi = mid; }
        int start = lo;
        lo = 0; hi = n;                     // upper_bound(b)
        while (lo < hi) { int mid = (lo + hi) >> 1; if (batch[mid] <= b) lo = mid + 1; else hi = mid; }
        cntB[b] = lo - start;
    }
}

__global__ void fc_kernel(const float* __restrict__ pooled, const int* __restrict__ cntB,
                          const float* __restrict__ Wfc, const float* __restrict__ bfc,
                          float* __restrict__ out) {
    int t = IDX;
    if (t < 50 * 10) {
        int b = t / 10, c = t % 10;
        float inv = 1.0f / fmaxf((float)cntB[b], 1.0f);
        float s = bfc[c];
        #pragma unroll
        for (int f = 0; f < 64; ++f)
            s = fmaf(pooled[b*64 + f] * inv, Wfc[f*10 + c], s);
        out[t] = s;
    }
}

extern "C" void kernel_launch(void* const* d_in, const int* in_sizes, int n_in,
                              void* d_out, int out_size, void* d_ws, size_t ws_size,
                              hipStream_t stream) {
    const float* x     = (const float*)d_in[0];
    const int*   ei    = (const int*)d_in[1];
    const int*   batch = (const int*)d_in[2];
    const float* W1    = (const float*)d_in[3];
    const float* b1    = (const float*)d_in[4];
    const float* W2    = (const float*)d_in[5];
    const float* b2    = (const float*)d_in[6];
    const float* Wfc   = (const float*)d_in[7];
    const float* bfc   = (const float*)d_in[8];
    float* out = (float*)d_out;

    const int n = in_sizes[2];          // 100000
    const int E = in_sizes[1] / 2;      // 1600000
    const int* src = ei;
    const int* dst = ei + E;

    // bump-allocate workspace (256B aligned regions)
    char* p = (char*)d_ws;
    auto alloc = [&](size_t bytes) { char* r = p; p += (bytes + 255) & ~(size_t)255; return r; };
    int*   cnt     = (int*)  alloc((size_t)n * 4);
    int*   cursor  = (int*)  alloc((size_t)n * 4);
    float* pooled  = (float*)alloc(50 * 64 * 4);
    size_t zbytes  = (size_t)(p - (char*)d_ws);      // zero-init region
    int*   cntB    = (int*)  alloc(50 * 4);
    int*   bsum    = (int*)  alloc(128 * 4);
    int*   rs      = (int*)  alloc((size_t)(n + 1) * 4);
    int2*  csr_pk  = (int2*) alloc((size_t)E * 8);
    float* dinv    = (float*)alloc((size_t)n * 4);
    float* winv    = (float*)alloc((size_t)n * 4);
    float* h_raw   = (float*)alloc((size_t)n * 128 * 4);
    float* h_act   = (float*)alloc((size_t)n * 128 * 4);

    hipMemsetAsync(d_ws, 0, zbytes, stream);

    int eb    = (E + 255) / 256;
    int nb256 = (n + 255) / 256;
    int nscan = (n + 1023) / 1024;      // 98 blocks (<=128 for scan2)

    count_deg<<<eb, 256, 0, stream>>>(dst, cnt, E);
    compute_dinv<<<nb256, 256, 0, stream>>>(cnt, dinv, winv, n);
    scan1<<<nscan, 256, 0, stream>>>(cnt, rs, bsum, n);
    scan2<<<1, 128, 0, stream>>>(bsum, nscan);
    scan3<<<nb256, 256, 0, stream>>>(rs, bsum, n, E);
    fill_csr<<<eb, 256, 0, stream>>>(src, dst, rs, cursor, dinv, csr_pk, E);

    // layer 1: h_raw = x @ W1 ; h_act = relu(agg(h_raw) + h_raw*winv + b1)
    dim3 g1((n + 63) / 64, 2);
    gemm_k128<<<g1, 256, 0, stream>>>(x, W1, h_raw, n, 128);
    int nagg = (n + 3) / 4;
    aggregate<128, false><<<nagg, 256, 0, stream>>>(h_raw, rs, csr_pk,
                                                    winv, b1, batch, pooled, h_act, n);

    // layer 2: h_raw(:, :64) = h_act @ W2 ; h_act(:, :64) = relu(...) + fused pooling
    dim3 g2((n + 63) / 64, 1);
    gemm_k128<<<g2, 256, 0, stream>>>(h_act, W2, h_raw, n, 64);
    graph_counts<<<1, 64, 0, stream>>>(batch, cntB, n, 50);
    aggregate<64, true><<<nagg, 256, 0, stream>>>(h_raw, rs, csr_pk,
                                                  winv, b2, batch, pooled, h_act, n);

    fc_kernel<<<1, 512, 0, stream>>>(pooled, cntB, Wfc, bfc, out);
}

// Round 12
// 650.056 us; speedup vs baseline: 1.8285x; 1.0230x over previous
//
#include <hip/hip_runtime.h>

// 2-layer GCN + mean-pool + FC. N=100000, E=1.6M, F=128, H=128, H2=64, B=50.
// R1: count_batch atomics -> 50 binary searches (567us -> ~0).
// R4: GEMM: xs[r][k] untransposed, 4x4 consecutive tile, ds_read_b128.
// R5 FAILED: sub-wave row sharding quadrupled aggregate (one-row-per-wave-
//            instruction is the coalescer-friendly unit). Reverted.
// R6: unroll-8 gathers: neutral (~210us) -> aggregate is L3-BW-bound at
//     ~4 TB/s effective, not latency-bound.
// R7: halve gather bytes: GEMM epilogue writes dinv-prescaled rows as bf16
//     (hs_j = bf16(dinv_j * (XW)_j)); out_i = relu(dinv_i*(sum hs_j + hs_i)+b)
//     exactly (winv=dinv^2 folds self-loop into the sum). CSR = src only
//     (4B/edge, fill_csr loses 2 random dinv gathers/edge). Layer-2 output
//     feeds only pooling -> no out store. fp32 accumulation throughout.
// R8-R11: resubmit (GPU acquisition timeouts, no data).

#define IDX (blockIdx.x * (int)blockDim.x + (int)threadIdx.x)

__device__ __forceinline__ unsigned short f2bf(float f) {   // RNE bf16
    union { float f; unsigned u; } c{f};
    unsigned u = c.u;
    return (unsigned short)((u + 0x7fffu + ((u >> 16) & 1u)) >> 16);
}

// ---------------- degree / normalization ----------------
__global__ void count_deg(const int* __restrict__ dst, int* __restrict__ cnt, int E) {
    int e = IDX;
    if (e < E) atomicAdd(&cnt[dst[e]], 1);
}

__global__ void compute_dinv(const int* __restrict__ cnt, float* __restrict__ dinv, int n) {
    int i = IDX;
    if (i < n) dinv[i] = 1.0f / sqrtf(1.0f + (float)cnt[i]);
}

// ---------------- exclusive scan over cnt (1024 items/block) ------
__global__ void scan1(const int* __restrict__ cnt, int* __restrict__ rs,
                      int* __restrict__ bsum, int n) {
    __shared__ int lds[256];
    int t = threadIdx.x;
    int base = blockIdx.x * 1024 + t * 4;
    int c0 = 0, c1 = 0, c2 = 0, c3 = 0;
    if (base + 3 < n) {
        int4 v = *(const int4*)&cnt[base];
        c0 = v.x; c1 = v.y; c2 = v.z; c3 = v.w;
    } else {
        if (base     < n) c0 = cnt[base];
        if (base + 1 < n) c1 = cnt[base + 1];
        if (base + 2 < n) c2 = cnt[base + 2];
        if (base + 3 < n) c3 = cnt[base + 3];
    }
    int s = c0 + c1 + c2 + c3;
    lds[t] = s; __syncthreads();
    for (int off = 1; off < 256; off <<= 1) {
        int v = (t >= off) ? lds[t - off] : 0;
        __syncthreads();
        lds[t] += v;
        __syncthreads();
    }
    int incl = lds[t];
    int excl = incl - s;
    if (t == 255) bsum[blockIdx.x] = incl;
    if (base     < n) rs[base]     = excl;
    if (base + 1 < n) rs[base + 1] = excl + c0;
    if (base + 2 < n) rs[base + 2] = excl + c0 + c1;
    if (base + 3 < n) rs[base + 3] = excl + c0 + c1 + c2;
}

__global__ void scan2(int* __restrict__ bsum, int nb) {   // nb <= 128
    __shared__ int lds[128];
    int t = threadIdx.x;
    int v = (t < nb) ? bsum[t] : 0;
    lds[t] = v; __syncthreads();
    for (int off = 1; off < 128; off <<= 1) {
        int u = (t >= off) ? lds[t - off] : 0;
        __syncthreads();
        lds[t] += u;
        __syncthreads();
    }
    if (t < nb) bsum[t] = lds[t] - v;   // exclusive
}

__global__ void scan3(int* __restrict__ rs, const int* __restrict__ bsum, int n, int E) {
    int i = IDX;
    if (i < n) rs[i] += bsum[i >> 10];
    if (i == 0) rs[n] = E;
}

// ---------------- CSR fill (counting sort by dst; src index only) -----------
__global__ void fill_csr(const int* __restrict__ src, const int* __restrict__ dst,
                         const int* __restrict__ rs, int* __restrict__ cursor,
                         int* __restrict__ csr, int E) {
    int e = IDX;
    if (e < E) {
        int d = dst[e];
        int p = rs[d] + atomicAdd(&cursor[d], 1);
        csr[p] = src[e];
    }
}

// ---------------- fp32 GEMM -> dinv-scaled bf16 rows ------------------------
// Y_bf[row][c] = bf16(dinv[row] * sum_k X[row][k] W[k][c]).  64x64 per block.
__global__ __launch_bounds__(256) void gemm_k128_bf(const float* __restrict__ X,
        const float* __restrict__ W, const float* __restrict__ dinv,
        unsigned short* __restrict__ Ybf, int nrows, int outw) {
    __shared__ float ws[128][64];   // ws[k][c]
    __shared__ float xs[64][128];   // xs[r][k]
    const int t = threadIdx.x;
    const int row0 = blockIdx.x * 64;
    const int c0 = blockIdx.y * 64;

    #pragma unroll
    for (int i = 0; i < 8; ++i) {
        int idx = i * 256 + t;
        int k = idx >> 4, cq = idx & 15;
        float4 v = *(const float4*)&W[(size_t)k * outw + c0 + cq * 4];
        *(float4*)&ws[k][cq * 4] = v;
    }
    #pragma unroll
    for (int i = 0; i < 8; ++i) {
        int idx = i * 256 + t;
        int r = idx >> 5, kq = idx & 31;
        float4 v = make_float4(0.f, 0.f, 0.f, 0.f);
        if (row0 + r < nrows) v = *(const float4*)&X[(size_t)(row0 + r) * 128 + kq * 4];
        *(float4*)&xs[r][kq * 4] = v;
    }
    __syncthreads();

    const int r0  = (t >> 4) * 4;
    const int cc0 = (t & 15) * 4;
    float acc[4][4] = {};
    #pragma unroll 2
    for (int k0 = 0; k0 < 128; k0 += 4) {
        float xv[4][4], wv[4][4];
        #pragma unroll
        for (int i = 0; i < 4; ++i)
            *(float4*)xv[i] = *(const float4*)&xs[r0 + i][k0];
        #pragma unroll
        for (int kk = 0; kk < 4; ++kk)
            *(float4*)wv[kk] = *(const float4*)&ws[k0 + kk][cc0];
        #pragma unroll
        for (int i = 0; i < 4; ++i)
            #pragma unroll
            for (int kk = 0; kk < 4; ++kk)
                #pragma unroll
                for (int j = 0; j < 4; ++j)
                    acc[i][j] = fmaf(xv[i][kk], wv[kk][j], acc[i][j]);
    }
    #pragma unroll
    for (int i = 0; i < 4; ++i) {
        int row = row0 + r0 + i;
        if (row < nrows) {
            float s = dinv[row];
            ushort4 st;
            st.x = f2bf(acc[i][0] * s); st.y = f2bf(acc[i][1] * s);
            st.z = f2bf(acc[i][2] * s); st.w = f2bf(acc[i][3] * s);
            *(ushort4*)&Ybf[(size_t)row * outw + c0 + cc0] = st;
        }
    }
}

// ---------------- gather aggregation over bf16 prescaled rows ---------------
// out_i = relu(dinv_i * (sum_{j in N(i)} hs_j + hs_i) + bias). One wave/node,
// one full row per memory instruction. FW=128: lane reads uint (2 bf16).
// FW=64: lane reads ushort; POOL accumulates into pooled (no out store).
template<int FW, bool POOL>
__global__ __launch_bounds__(256) void aggregate_bf(
        const unsigned short* __restrict__ hbf, const int* __restrict__ rs,
        const int* __restrict__ csr, const float* __restrict__ dinv,
        const float* __restrict__ bias, const int* __restrict__ batch,
        float* __restrict__ pooled, float* __restrict__ out, int n) {
    int node = blockIdx.x * 4 + ((int)threadIdx.x >> 6);
    int lane = (int)threadIdx.x & 63;
    if (node >= n) return;
    const int b0 = rs[node], b1 = rs[node + 1];

    float a0 = 0.f, a1 = 0.f;
    int e = b0;
    for (; e + 8 <= b1; e += 8) {
        int s0 = csr[e],   s1 = csr[e+1], s2 = csr[e+2], s3 = csr[e+3];
        int s4 = csr[e+4], s5 = csr[e+5], s6 = csr[e+6], s7 = csr[e+7];
        if (FW == 128) {
            unsigned v0 = *(const unsigned*)&hbf[(size_t)s0*128 + lane*2];
            unsigned v1 = *(const unsigned*)&hbf[(size_t)s1*128 + lane*2];
            unsigned v2 = *(const unsigned*)&hbf[(size_t)s2*128 + lane*2];
            unsigned v3 = *(const unsigned*)&hbf[(size_t)s3*128 + lane*2];
            unsigned v4 = *(const unsigned*)&hbf[(size_t)s4*128 + lane*2];
            unsigned v5 = *(const unsigned*)&hbf[(size_t)s5*128 + lane*2];
            unsigned v6 = *(const unsigned*)&hbf[(size_t)s6*128 + lane*2];
            unsigned v7 = *(const unsigned*)&hbf[(size_t)s7*128 + lane*2];
            a0 += (__uint_as_float(v0 << 16) + __uint_as_float(v1 << 16))
                + (__uint_as_float(v2 << 16) + __uint_as_float(v3 << 16))
                + (__uint_as_float(v4 << 16) + __uint_as_float(v5 << 16))
                + (__uint_as_float(v6 << 16) + __uint_as_float(v7 << 16));
            a1 += (__uint_as_float(v0 & 0xffff0000u) + __uint_as_float(v1 & 0xffff0000u))
                + (__uint_as_float(v2 & 0xffff0000u) + __uint_as_float(v3 & 0xffff0000u))
                + (__uint_as_float(v4 & 0xffff0000u) + __uint_as_float(v5 & 0xffff0000u))
                + (__uint_as_float(v6 & 0xffff0000u) + __uint_as_float(v7 & 0xffff0000u));
        } else {
            unsigned u0 = hbf[(size_t)s0*64 + lane], u1 = hbf[(size_t)s1*64 + lane];
            unsigned u2 = hbf[(size_t)s2*64 + lane], u3 = hbf[(size_t)s3*64 + lane];
            unsigned u4 = hbf[(size_t)s4*64 + lane], u5 = hbf[(size_t)s5*64 + lane];
            unsigned u6 = hbf[(size_t)s6*64 + lane], u7 = hbf[(size_t)s7*64 + lane];
            a0 += (__uint_as_float(u0 << 16) + __uint_as_float(u1 << 16))
                + (__uint_as_float(u2 << 16) + __uint_as_float(u3 << 16))
                + (__uint_as_float(u4 << 16) + __uint_as_float(u5 << 16))
                + (__uint_as_float(u6 << 16) + __uint_as_float(u7 << 16));
        }
    }
    for (; e < b1; ++e) {
        int s = csr[e];
        if (FW == 128) {
            unsigned v = *(const unsigned*)&hbf[(size_t)s*128 + lane*2];
            a0 += __uint_as_float(v << 16);
            a1 += __uint_as_float(v & 0xffff0000u);
        } else {
            a0 += __uint_as_float((unsigned)hbf[(size_t)s*64 + lane] << 16);
        }
    }

    const float dn = dinv[node];
    if (FW == 128) {
        unsigned vs = *(const unsigned*)&hbf[(size_t)node*128 + lane*2];
        a0 += __uint_as_float(vs << 16);
        a1 += __uint_as_float(vs & 0xffff0000u);
        float2 bv = *(const float2*)&bias[lane*2];
        float o0 = fmaxf(fmaf(a0, dn, bv.x), 0.f);
        float o1 = fmaxf(fmaf(a1, dn, bv.y), 0.f);
        *(float2*)&out[(size_t)node*128 + lane*2] = make_float2(o0, o1);
    } else {
        a0 += __uint_as_float((unsigned)hbf[(size_t)node*64 + lane] << 16);
        float o = fmaxf(fmaf(a0, dn, bias[lane]), 0.f);
        if (POOL) atomicAdd(&pooled[(size_t)batch[node]*64 + lane], o);
        else out[(size_t)node*64 + lane] = o;
    }
}

// ---------------- pooling counts (batch SORTED -> binary search) ------------
__global__ void graph_counts(const int* __restrict__ batch, int* __restrict__ cntB,
                             int n, int B) {
    int b = (int)threadIdx.x;
    if (b < B) {
        int lo = 0, hi = n;
        while (lo < hi) { int mid = (lo + hi) >> 1; if (batch[mid] < b) lo = mid + 1; else hi = mid; }
        int start = lo;
        lo = 0; hi = n;
        while (lo < hi) { int mid = (lo + hi) >> 1; if (batch[mid] <= b) lo = mid + 1; else hi = mid; }
        cntB[b] = lo - start;
    }
}

__global__ void fc_kernel(const float* __restrict__ pooled, const int* __restrict__ cntB,
                          const float* __restrict__ Wfc, const float* __restrict__ bfc,
                          float* __restrict__ out) {
    int t = IDX;
    if (t < 50 * 10) {
        int b = t / 10, c = t % 10;
        float inv = 1.0f / fmaxf((float)cntB[b], 1.0f);
        float s = bfc[c];
        #pragma unroll
        for (int f = 0; f < 64; ++f)
            s = fmaf(pooled[b*64 + f] * inv, Wfc[f*10 + c], s);
        out[t] = s;
    }
}

extern "C" void kernel_launch(void* const* d_in, const int* in_sizes, int n_in,
                              void* d_out, int out_size, void* d_ws, size_t ws_size,
                              hipStream_t stream) {
    const float* x     = (const float*)d_in[0];
    const int*   ei    = (const int*)d_in[1];
    const int*   batch = (const int*)d_in[2];
    const float* W1    = (const float*)d_in[3];
    const float* b1    = (const float*)d_in[4];
    const float* W2    = (const float*)d_in[5];
    const float* b2    = (const float*)d_in[6];
    const float* Wfc   = (const float*)d_in[7];
    const float* bfc   = (const float*)d_in[8];
    float* out = (float*)d_out;

    const int n = in_sizes[2];          // 100000
    const int E = in_sizes[1] / 2;      // 1600000
    const int* src = ei;
    const int* dst = ei + E;

    // bump-allocate workspace (256B aligned regions)
    char* p = (char*)d_ws;
    auto alloc = [&](size_t bytes) { char* r = p; p += (bytes + 255) & ~(size_t)255; return r; };
    int*   cnt     = (int*)  alloc((size_t)n * 4);
    int*   cursor  = (int*)  alloc((size_t)n * 4);
    float* pooled  = (float*)alloc(50 * 64 * 4);
    size_t zbytes  = (size_t)(p - (char*)d_ws);      // zero-init region
    int*   cntB    = (int*)  alloc(50 * 4);
    int*   bsum    = (int*)  alloc(128 * 4);
    int*   rs      = (int*)  alloc((size_t)(n + 1) * 4);
    int*   csr     = (int*)  alloc((size_t)E * 4);
    float* dinv    = (float*)alloc((size_t)n * 4);
    unsigned short* hbf1 = (unsigned short*)alloc((size_t)n * 128 * 2);
    unsigned short* hbf2 = (unsigned short*)alloc((size_t)n * 64 * 2);
    float* h_act   = (float*)alloc((size_t)n * 128 * 4);

    hipMemsetAsync(d_ws, 0, zbytes, stream);

    int eb    = (E + 255) / 256;
    int nb256 = (n + 255) / 256;
    int nscan = (n + 1023) / 1024;      // 98 blocks (<=128 for scan2)

    count_deg<<<eb, 256, 0, stream>>>(dst, cnt, E);
    compute_dinv<<<nb256, 256, 0, stream>>>(cnt, dinv, n);
    scan1<<<nscan, 256, 0, stream>>>(cnt, rs, bsum, n);
    scan2<<<1, 128, 0, stream>>>(bsum, nscan);
    scan3<<<nb256, 256, 0, stream>>>(rs, bsum, n, E);
    fill_csr<<<eb, 256, 0, stream>>>(src, dst, rs, cursor, csr, E);

    // layer 1: hbf1 = bf16(dinv * (x @ W1)); h_act = relu(dinv*(sum+self)+b1)
    dim3 g1((n + 63) / 64, 2);
    gemm_k128_bf<<<g1, 256, 0, stream>>>(x, W1, dinv, hbf1, n, 128);
    int nagg = (n + 3) / 4;
    aggregate_bf<128, false><<<nagg, 256, 0, stream>>>(hbf1, rs, csr, dinv,
                                                       b1, batch, pooled, h_act, n);

    // layer 2: hbf2 = bf16(dinv * (h_act @ W2)); pooled += relu(...)
    dim3 g2((n + 63) / 64, 1);
    gemm_k128_bf<<<g2, 256, 0, stream>>>(h_act, W2, dinv, hbf2, n, 64);
    graph_counts<<<1, 64, 0, stream>>>(batch, cntB, n, 50);
    aggregate_bf<64, true><<<nagg, 256, 0, stream>>>(hbf2, rs, csr, dinv,
                                                     b2, batch, pooled, nullptr, n);

    fc_kernel<<<1, 512, 0, stream>>>(pooled, cntB, Wfc, bfc, out);
}

// Round 13
// 645.562 us; speedup vs baseline: 1.8412x; 1.0070x over previous
//
#include <hip/hip_runtime.h>

// 2-layer GCN + mean-pool + FC. N=100000, E=1.6M, F=128, H=128, H2=64, B=50.
// R1: count_batch atomics -> 50 binary searches (567us -> ~0).
// R4: GEMM: xs[r][k] untransposed, 4x4 consecutive tile, ds_read_b128.
// R5 FAILED: sub-wave row sharding (multi-row per memory instruction) 4x'd
//            aggregate. One-row-per-wave-instruction is the unit.
// R6: unroll-8: neutral. R7: bf16 payload halved bytes: neutral TIME
//     (230us, FETCH 195->87MB) -> aggregate is REQUEST-bound, not byte-bound.
// R12: padded CSR (each node's segment padded to 8 with sentinel row n = zero
//      row; exact zeros added). Segments 8-aligned -> idx loads are 2x int4
//      per 8 gathers (vmem inst/edge 2.0 -> 1.25), no tail, uniform flow.

#define IDX (blockIdx.x * (int)blockDim.x + (int)threadIdx.x)

__device__ __forceinline__ unsigned short f2bf(float f) {   // RNE bf16
    union { float f; unsigned u; } c{f};
    unsigned u = c.u;
    return (unsigned short)((u + 0x7fffu + ((u >> 16) & 1u)) >> 16);
}

// ---------------- degree / normalization ----------------
__global__ void count_deg(const int* __restrict__ dst, int* __restrict__ cnt, int E) {
    int e = IDX;
    if (e < E) atomicAdd(&cnt[dst[e]], 1);
}

__global__ void compute_dinv(const int* __restrict__ cnt, float* __restrict__ dinv, int n) {
    int i = IDX;
    if (i < n) dinv[i] = 1.0f / sqrtf(1.0f + (float)cnt[i]);
}

// ------- exclusive scan over PADDED counts, m = n+1 items (cnt[n]:=0) -------
// padded count = (cnt[i]+7) & ~7  -> every segment is a multiple of 8.
__global__ void scan1(const int* __restrict__ cnt, int* __restrict__ rs,
                      int* __restrict__ bsum, int n, int m) {
    __shared__ int lds[256];
    int t = threadIdx.x;
    int base = blockIdx.x * 1024 + t * 4;
    int c0 = 0, c1 = 0, c2 = 0, c3 = 0;
    if (base     < n) c0 = (cnt[base]     + 7) & ~7;
    if (base + 1 < n) c1 = (cnt[base + 1] + 7) & ~7;
    if (base + 2 < n) c2 = (cnt[base + 2] + 7) & ~7;
    if (base + 3 < n) c3 = (cnt[base + 3] + 7) & ~7;
    int s = c0 + c1 + c2 + c3;
    lds[t] = s; __syncthreads();
    for (int off = 1; off < 256; off <<= 1) {
        int v = (t >= off) ? lds[t - off] : 0;
        __syncthreads();
        lds[t] += v;
        __syncthreads();
    }
    int incl = lds[t];
    int excl = incl - s;
    if (t == 255) bsum[blockIdx.x] = incl;
    if (base     < m) rs[base]     = excl;
    if (base + 1 < m) rs[base + 1] = excl + c0;
    if (base + 2 < m) rs[base + 2] = excl + c0 + c1;
    if (base + 3 < m) rs[base + 3] = excl + c0 + c1 + c2;
}

__global__ void scan2(int* __restrict__ bsum, int nb) {   // nb <= 128
    __shared__ int lds[128];
    int t = threadIdx.x;
    int v = (t < nb) ? bsum[t] : 0;
    lds[t] = v; __syncthreads();
    for (int off = 1; off < 128; off <<= 1) {
        int u = (t >= off) ? lds[t - off] : 0;
        __syncthreads();
        lds[t] += u;
        __syncthreads();
    }
    if (t < nb) bsum[t] = lds[t] - v;   // exclusive
}

__global__ void scan3(int* __restrict__ rs, const int* __restrict__ bsum, int m) {
    int i = IDX;
    if (i < m) rs[i] += bsum[i >> 10];
}

// ---------------- CSR init (sentinel) + fill ----------------
__global__ void csr_init(int* __restrict__ csr, int sentinel, int len) {
    int i = IDX;
    if (i < len) csr[i] = sentinel;
}

__global__ void fill_csr(const int* __restrict__ src, const int* __restrict__ dst,
                         const int* __restrict__ rs, int* __restrict__ cursor,
                         int* __restrict__ csr, int E) {
    int e = IDX;
    if (e < E) {
        int d = dst[e];
        int p = rs[d] + atomicAdd(&cursor[d], 1);
        csr[p] = src[e];
    }
}

// zero rows at index n of hbf1 (128) and hbf2 (64)
__global__ void zero_pad_rows(unsigned short* __restrict__ hbf1,
                              unsigned short* __restrict__ hbf2, int n) {
    int t = (int)threadIdx.x;
    if (t < 128) hbf1[(size_t)n * 128 + t] = 0;
    if (t < 64)  hbf2[(size_t)n * 64 + t] = 0;
}

// ---------------- fp32 GEMM -> dinv-scaled bf16 rows ------------------------
__global__ __launch_bounds__(256) void gemm_k128_bf(const float* __restrict__ X,
        const float* __restrict__ W, const float* __restrict__ dinv,
        unsigned short* __restrict__ Ybf, int nrows, int outw) {
    __shared__ float ws[128][64];   // ws[k][c]
    __shared__ float xs[64][128];   // xs[r][k]
    const int t = threadIdx.x;
    const int row0 = blockIdx.x * 64;
    const int c0 = blockIdx.y * 64;

    #pragma unroll
    for (int i = 0; i < 8; ++i) {
        int idx = i * 256 + t;
        int k = idx >> 4, cq = idx & 15;
        float4 v = *(const float4*)&W[(size_t)k * outw + c0 + cq * 4];
        *(float4*)&ws[k][cq * 4] = v;
    }
    #pragma unroll
    for (int i = 0; i < 8; ++i) {
        int idx = i * 256 + t;
        int r = idx >> 5, kq = idx & 31;
        float4 v = make_float4(0.f, 0.f, 0.f, 0.f);
        if (row0 + r < nrows) v = *(const float4*)&X[(size_t)(row0 + r) * 128 + kq * 4];
        *(float4*)&xs[r][kq * 4] = v;
    }
    __syncthreads();

    const int r0  = (t >> 4) * 4;
    const int cc0 = (t & 15) * 4;
    float acc[4][4] = {};
    #pragma unroll 2
    for (int k0 = 0; k0 < 128; k0 += 4) {
        float xv[4][4], wv[4][4];
        #pragma unroll
        for (int i = 0; i < 4; ++i)
            *(float4*)xv[i] = *(const float4*)&xs[r0 + i][k0];
        #pragma unroll
        for (int kk = 0; kk < 4; ++kk)
            *(float4*)wv[kk] = *(const float4*)&ws[k0 + kk][cc0];
        #pragma unroll
        for (int i = 0; i < 4; ++i)
            #pragma unroll
            for (int kk = 0; kk < 4; ++kk)
                #pragma unroll
                for (int j = 0; j < 4; ++j)
                    acc[i][j] = fmaf(xv[i][kk], wv[kk][j], acc[i][j]);
    }
    #pragma unroll
    for (int i = 0; i < 4; ++i) {
        int row = row0 + r0 + i;
        if (row < nrows) {
            float s = dinv[row];
            ushort4 st;
            st.x = f2bf(acc[i][0] * s); st.y = f2bf(acc[i][1] * s);
            st.z = f2bf(acc[i][2] * s); st.w = f2bf(acc[i][3] * s);
            *(ushort4*)&Ybf[(size_t)row * outw + c0 + cc0] = st;
        }
    }
}

// ---------------- gather aggregation over bf16 prescaled rows ---------------
// Padded CSR: every segment length % 8 == 0, 8-aligned start. Per 8 edges:
// two int4 index loads + 8 row gathers. Dummy entries (== n) hit the zero row.
template<int FW, bool POOL>
__global__ __launch_bounds__(256) void aggregate_bf(
        const unsigned short* __restrict__ hbf, const int* __restrict__ rs,
        const int* __restrict__ csr, const float* __restrict__ dinv,
        const float* __restrict__ bias, const int* __restrict__ batch,
        float* __restrict__ pooled, float* __restrict__ out, int n) {
    int node = blockIdx.x * 4 + ((int)threadIdx.x >> 6);
    int lane = (int)threadIdx.x & 63;
    if (node >= n) return;
    const int b0 = rs[node], b1 = rs[node + 1];

    float a0 = 0.f, a1 = 0.f;
    for (int e = b0; e < b1; e += 8) {
        int4 ia = *(const int4*)&csr[e];
        int4 ib = *(const int4*)&csr[e + 4];
        if (FW == 128) {
            unsigned v0 = *(const unsigned*)&hbf[(size_t)ia.x*128 + lane*2];
            unsigned v1 = *(const unsigned*)&hbf[(size_t)ia.y*128 + lane*2];
            unsigned v2 = *(const unsigned*)&hbf[(size_t)ia.z*128 + lane*2];
            unsigned v3 = *(const unsigned*)&hbf[(size_t)ia.w*128 + lane*2];
            unsigned v4 = *(const unsigned*)&hbf[(size_t)ib.x*128 + lane*2];
            unsigned v5 = *(const unsigned*)&hbf[(size_t)ib.y*128 + lane*2];
            unsigned v6 = *(const unsigned*)&hbf[(size_t)ib.z*128 + lane*2];
            unsigned v7 = *(const unsigned*)&hbf[(size_t)ib.w*128 + lane*2];
            a0 += (__uint_as_float(v0 << 16) + __uint_as_float(v1 << 16))
                + (__uint_as_float(v2 << 16) + __uint_as_float(v3 << 16))
                + (__uint_as_float(v4 << 16) + __uint_as_float(v5 << 16))
                + (__uint_as_float(v6 << 16) + __uint_as_float(v7 << 16));
            a1 += (__uint_as_float(v0 & 0xffff0000u) + __uint_as_float(v1 & 0xffff0000u))
                + (__uint_as_float(v2 & 0xffff0000u) + __uint_as_float(v3 & 0xffff0000u))
                + (__uint_as_float(v4 & 0xffff0000u) + __uint_as_float(v5 & 0xffff0000u))
                + (__uint_as_float(v6 & 0xffff0000u) + __uint_as_float(v7 & 0xffff0000u));
        } else {
            unsigned u0 = hbf[(size_t)ia.x*64 + lane], u1 = hbf[(size_t)ia.y*64 + lane];
            unsigned u2 = hbf[(size_t)ia.z*64 + lane], u3 = hbf[(size_t)ia.w*64 + lane];
            unsigned u4 = hbf[(size_t)ib.x*64 + lane], u5 = hbf[(size_t)ib.y*64 + lane];
            unsigned u6 = hbf[(size_t)ib.z*64 + lane], u7 = hbf[(size_t)ib.w*64 + lane];
            a0 += (__uint_as_float(u0 << 16) + __uint_as_float(u1 << 16))
                + (__uint_as_float(u2 << 16) + __uint_as_float(u3 << 16))
                + (__uint_as_float(u4 << 16) + __uint_as_float(u5 << 16))
                + (__uint_as_float(u6 << 16) + __uint_as_float(u7 << 16));
        }
    }

    const float dn = dinv[node];
    if (FW == 128) {
        unsigned vs = *(const unsigned*)&hbf[(size_t)node*128 + lane*2];
        a0 += __uint_as_float(vs << 16);
        a1 += __uint_as_float(vs & 0xffff0000u);
        float2 bv = *(const float2*)&bias[lane*2];
        float o0 = fmaxf(fmaf(a0, dn, bv.x), 0.f);
        float o1 = fmaxf(fmaf(a1, dn, bv.y), 0.f);
        *(float2*)&out[(size_t)node*128 + lane*2] = make_float2(o0, o1);
    } else {
        a0 += __uint_as_float((unsigned)hbf[(size_t)node*64 + lane] << 16);
        float o = fmaxf(fmaf(a0, dn, bias[lane]), 0.f);
        if (POOL) atomicAdd(&pooled[(size_t)batch[node]*64 + lane], o);
        else out[(size_t)node*64 + lane] = o;
    }
}

// ---------------- pooling counts (batch SORTED -> binary search) ------------
__global__ void graph_counts(const int* __restrict__ batch, int* __restrict__ cntB,
                             int n, int B) {
    int b = (int)threadIdx.x;
    if (b < B) {
        int lo = 0, hi = n;
        while (lo < hi) { int mid = (lo + hi) >> 1; if (batch[mid] < b) lo = mid + 1; else hi = mid; }
        int start = lo;
        lo = 0; hi = n;
        while (lo < hi) { int mid = (lo + hi) >> 1; if (batch[mid] <= b) lo = mid + 1; else hi = mid; }
        cntB[b] = lo - start;
    }
}

__global__ void fc_kernel(const float* __restrict__ pooled, const int* __restrict__ cntB,
                          const float* __restrict__ Wfc, const float* __restrict__ bfc,
                          float* __restrict__ out) {
    int t = IDX;
    if (t < 50 * 10) {
        int b = t / 10, c = t % 10;
        float inv = 1.0f / fmaxf((float)cntB[b], 1.0f);
        float s = bfc[c];
        #pragma unroll
        for (int f = 0; f < 64; ++f)
            s = fmaf(pooled[b*64 + f] * inv, Wfc[f*10 + c], s);
        out[t] = s;
    }
}

extern "C" void kernel_launch(void* const* d_in, const int* in_sizes, int n_in,
                              void* d_out, int out_size, void* d_ws, size_t ws_size,
                              hipStream_t stream) {
    const float* x     = (const float*)d_in[0];
    const int*   ei    = (const int*)d_in[1];
    const int*   batch = (const int*)d_in[2];
    const float* W1    = (const float*)d_in[3];
    const float* b1    = (const float*)d_in[4];
    const float* W2    = (const float*)d_in[5];
    const float* b2    = (const float*)d_in[6];
    const float* Wfc   = (const float*)d_in[7];
    const float* bfc   = (const float*)d_in[8];
    float* out = (float*)d_out;

    const int n = in_sizes[2];          // 100000
    const int E = in_sizes[1] / 2;      // 1600000
    const int Epad = E + 8 * n;         // max padded CSR length
    const int* src = ei;
    const int* dst = ei + E;

    // bump-allocate workspace (256B aligned regions)
    char* p = (char*)d_ws;
    auto alloc = [&](size_t bytes) { char* r = p; p += (bytes + 255) & ~(size_t)255; return r; };
    int*   cnt     = (int*)  alloc((size_t)n * 4);
    int*   cursor  = (int*)  alloc((size_t)n * 4);
    float* pooled  = (float*)alloc(50 * 64 * 4);
    size_t zbytes  = (size_t)(p - (char*)d_ws);      // zero-init region
    int*   cntB    = (int*)  alloc(50 * 4);
    int*   bsum    = (int*)  alloc(128 * 4);
    int*   rs      = (int*)  alloc((size_t)(n + 1) * 4);
    int*   csr     = (int*)  alloc((size_t)Epad * 4);
    float* dinv    = (float*)alloc((size_t)n * 4);
    unsigned short* hbf1 = (unsigned short*)alloc((size_t)(n + 1) * 128 * 2);
    unsigned short* hbf2 = (unsigned short*)alloc((size_t)(n + 1) * 64 * 2);
    float* h_act   = (float*)alloc((size_t)n * 128 * 4);

    hipMemsetAsync(d_ws, 0, zbytes, stream);

    const int m = n + 1;                 // scan domain (rs has n+1 entries)
    int eb    = (E + 255) / 256;
    int epb   = (Epad + 255) / 256;
    int nb256 = (n + 255) / 256;
    int mb256 = (m + 255) / 256;
    int nscan = (m + 1023) / 1024;       // 99 blocks (<=128 for scan2)

    count_deg<<<eb, 256, 0, stream>>>(dst, cnt, E);
    compute_dinv<<<nb256, 256, 0, stream>>>(cnt, dinv, n);
    scan1<<<nscan, 256, 0, stream>>>(cnt, rs, bsum, n, m);
    scan2<<<1, 128, 0, stream>>>(bsum, nscan);
    scan3<<<mb256, 256, 0, stream>>>(rs, bsum, m);
    csr_init<<<epb, 256, 0, stream>>>(csr, n, Epad);
    fill_csr<<<eb, 256, 0, stream>>>(src, dst, rs, cursor, csr, E);
    zero_pad_rows<<<1, 128, 0, stream>>>(hbf1, hbf2, n);

    // layer 1: hbf1 = bf16(dinv * (x @ W1)); h_act = relu(dinv*(sum+self)+b1)
    dim3 g1((n + 63) / 64, 2);
    gemm_k128_bf<<<g1, 256, 0, stream>>>(x, W1, dinv, hbf1, n, 128);
    int nagg = (n + 3) / 4;
    aggregate_bf<128, false><<<nagg, 256, 0, stream>>>(hbf1, rs, csr, dinv,
                                                       b1, batch, pooled, h_act, n);

    // layer 2: hbf2 = bf16(dinv * (h_act @ W2)); pooled += relu(...)
    dim3 g2((n + 63) / 64, 1);
    gemm_k128_bf<<<g2, 256, 0, stream>>>(h_act, W2, dinv, hbf2, n, 64);
    graph_counts<<<1, 64, 0, stream>>>(batch, cntB, n, 50);
    aggregate_bf<64, true><<<nagg, 256, 0, stream>>>(hbf2, rs, csr, dinv,
                                                     b2, batch, pooled, nullptr, n);

    fc_kernel<<<1, 512, 0, stream>>>(pooled, cntB, Wfc, bfc, out);
}